// Round 9
// baseline (84.306 us; speedup 1.0000x reference)
//
#include <hip/hip_runtime.h>
#include <hip/hip_bf16.h>
#include <math.h>

#define BB 8
#define NN 2048
#define CC 128
#define DD 128

typedef __attribute__((ext_vector_type(8))) short short8;
typedef __attribute__((ext_vector_type(4))) float f32x4;

static __device__ __forceinline__ unsigned short f2bf(float f) {
    __hip_bfloat16 h = __float2bfloat16(f);
    return *reinterpret_cast<unsigned short*>(&h);
}
static __device__ __forceinline__ float bf2f(unsigned short u) {
    __hip_bfloat16 h = *reinterpret_cast<__hip_bfloat16*>(&u);
    return __bfloat162float(h);
}

// ---------------- Kernel P: pack adj bitmask + split W hi/lo
#define PACK_BLOCKS (NN * NN / 256)          // 16384
#define WSPL_BLOCKS (DD * CC / 256)          // 64
__global__ __launch_bounds__(256) void prep_kernel(
    const int* __restrict__ adj, unsigned int* __restrict__ padj,
    const float* __restrict__ W,
    unsigned short* __restrict__ Whi, unsigned short* __restrict__ Wlo)
{
    const int bx  = blockIdx.x;
    const int tid = threadIdx.x;
    if (bx < PACK_BLOCKS) {
        const int idx  = bx * 256 + tid;
        const int i    = idx >> 11;
        const int j    = idx & 2047;
        const int lane = tid & 63;
        int ad = adj[(size_t)i * NN + j];
        unsigned long long m = __ballot(ad > 0);
        if (lane == 0)  padj[i * 64 + (j >> 5)] = (unsigned int)m;
        if (lane == 32) padj[i * 64 + (j >> 5)] = (unsigned int)(m >> 32);
    } else {
        const int g = (bx - PACK_BLOCKS) * 256 + tid;
        float w = W[g];
        unsigned short h = f2bf(w);
        Whi[g] = h;
        Wlo[g] = f2bf(w - bf2f(h));
    }
}

// ---------------- Kernel A: Wh = x @ W^T via compensated MFMA.
__global__ __launch_bounds__(256) void wh_kernel(
    const float* __restrict__ x,
    const unsigned short* __restrict__ Whi, const unsigned short* __restrict__ Wlo,
    const float* __restrict__ a,
    unsigned short* __restrict__ WhbT,
    float* __restrict__ f1, unsigned int* __restrict__ EGp)
{
    const int tid  = threadIdx.x;
    const int b    = blockIdx.y;
    const int n0   = blockIdx.x * 64;
    const int w    = tid >> 6;
    const int lane = tid & 63;
    const int fr   = lane & 15, fk = lane >> 4;
    const int n    = n0 + w * 16 + fr;

    short8 bh[4], bl[4];
    const float* xrow = &x[((size_t)(b * NN) + n) * CC];
    #pragma unroll
    for (int ks = 0; ks < 4; ++ks) {
        float xv[8];
        *(float4*)&xv[0] = *(const float4*)&xrow[(ks * 4 + fk) * 8];
        *(float4*)&xv[4] = *(const float4*)&xrow[(ks * 4 + fk) * 8 + 4];
        #pragma unroll
        for (int e = 0; e < 8; ++e) {
            unsigned short h = f2bf(xv[e]);
            bh[ks][e] = (short)h;
            bl[ks][e] = (short)f2bf(xv[e] - bf2f(h));
        }
    }

    f32x4 acc[8];
    #pragma unroll
    for (int dt = 0; dt < 8; ++dt) acc[dt] = (f32x4){0.f, 0.f, 0.f, 0.f};

    #pragma unroll
    for (int dt = 0; dt < 8; ++dt) {
        #pragma unroll
        for (int ks = 0; ks < 4; ++ks) {
            const int off = (dt * 16 + fr) * CC + (ks * 4 + fk) * 8;
            short8 aH = *(const short8*)&Whi[off];
            short8 aL = *(const short8*)&Wlo[off];
            acc[dt] = __builtin_amdgcn_mfma_f32_16x16x32_bf16(aH, bh[ks], acc[dt], 0, 0, 0);
            acc[dt] = __builtin_amdgcn_mfma_f32_16x16x32_bf16(aH, bl[ks], acc[dt], 0, 0, 0);
            acc[dt] = __builtin_amdgcn_mfma_f32_16x16x32_bf16(aL, bh[ks], acc[dt], 0, 0, 0);
        }
    }

    float p1 = 0.f, p2 = 0.f;
    #pragma unroll
    for (int dt = 0; dt < 8; ++dt) {
        #pragma unroll
        for (int r = 0; r < 4; ++r) {
            const int d = dt * 16 + fk * 4 + r;
            p1 += acc[dt][r] * a[d];
            p2 += acc[dt][r] * a[DD + d];
        }
    }
    p1 += __shfl_xor(p1, 16); p1 += __shfl_xor(p1, 32);
    p2 += __shfl_xor(p2, 16); p2 += __shfl_xor(p2, 32);
    if (fk == 0) {
        f1[b * NN + n] = p1;
        unsigned short e2 = f2bf(__expf(p2));
        unsigned short g2 = f2bf(__expf(0.2f * p2));
        EGp[b * NN + n] = (unsigned int)e2 | ((unsigned int)g2 << 16);
    }

    #pragma unroll
    for (int dt = 0; dt < 8; ++dt) {
        #pragma unroll
        for (int r = 0; r < 4; ++r) {
            const int d = dt * 16 + fk * 4 + r;
            WhbT[((size_t)(b * 128 + d)) * NN + n] = f2bf(acc[dt][r]);
        }
    }
}

// ---------------- Kernel C: MFMA attention. Block 64i x 128d, 4 waves (2x2),
// P computed IN REGISTERS (no P LDS round-trip); only B staged, XOR-swizzled,
// double-buffered, 1 barrier/chunk, 2-deep global prefetch.
template<int S, bool DIRECT>
__global__ __launch_bounds__(256, 4) void gat_kernel(
    const unsigned short* __restrict__ WhbT,   // [b][128 d][2048 n] bf16
    const unsigned int* __restrict__ padj,     // [2048][64] bitmask
    const float* __restrict__ f1,
    const unsigned int* __restrict__ EGp,      // packed bf16 (E2,G2)
    float* __restrict__ out,
    float* __restrict__ pPV, float* __restrict__ pS)
{
    constexpr int JS = NN / S;
    constexpr int NC = JS / 64;
    // B tile frag-linear w/ XOR swizzle: element (d, jloc) ->
    //   idx16 = ((d>>4)*2 + (jloc>>5))*64 + ((jloc>>3)&3)*16 + ((d&15) ^ ((jloc>>3 << 1) & 15))
    __shared__ __align__(16) unsigned short BsL[2][128 * 64];   // 2 x 16 KB
    __shared__ unsigned int EGs[JS];                             // JS*4 B
    __shared__ float Srow[64];
    __shared__ float Sred[64];

    const int tid   = threadIdx.x;
    const int i0    = blockIdx.x * 64;
    const int split = blockIdx.y;
    const int b     = blockIdx.z;
    const int jBeg  = split * JS;

    // stage EG row for this split (uint4 granularity)
    #pragma unroll
    for (int k = 0; k < JS / 1024; ++k)
        ((uint4*)EGs)[tid + 256 * k] =
            *(const uint4*)(EGp + b * NN + jBeg + (tid + 256 * k) * 4);

    const int w    = tid >> 6;
    const int wr   = w >> 1, wc = w & 1;
    const int lane = tid & 63;
    const int fr   = lane & 15, fk = lane >> 4;

    // per-lane row constants (it = 0,1)
    const int irow0 = i0 + wr * 32 + fr;
    const float f10 = f1[b * NN + irow0];
    const float f11 = f1[b * NN + irow0 + 16];
    const float e1_0 = __expf(f10),        e1_1 = __expf(f11);
    const float g1_0 = __expf(0.2f * f10), g1_1 = __expf(0.2f * f11);
    const unsigned int* mrow0 = padj + (size_t)irow0 * 64 + (jBeg >> 5);
    const unsigned int* mrow1 = mrow0 + 16 * 64;

    // B staging maps: 4 slots/thread, slot s = tid + 256*k
    const unsigned short* gB[4];
    int ldsOff[4];
    #pragma unroll
    for (int k = 0; k < 4; ++k) {
        const int s  = tid + 256 * k;
        const int dS = s >> 3, js = s & 7;
        gB[k] = WhbT + (size_t)(b * 128 + dS) * NN + jBeg + js * 8;
        ldsOff[k] = ((dS >> 4) * 2 + (js >> 2)) * 512 + (js & 3) * 128
                  + (((dS & 15) ^ ((js << 1) & 15)) << 3);
    }
    // B read offsets per ks (within tile): fk*128 + swizzled fr
    const int rb0 = fk * 128 + ((fr ^ (((0 * 4 + fk) << 1) & 15)) << 3);
    const int rb1 = fk * 128 + ((fr ^ (((1 * 4 + fk) << 1) & 15)) << 3);

    f32x4 acc[2][4];
    #pragma unroll
    for (int it = 0; it < 2; ++it)
        #pragma unroll
        for (int dtl = 0; dtl < 4; ++dtl) acc[it][dtl] = (f32x4){0.f,0.f,0.f,0.f};

    float sp0 = 0.f, sp1 = 0.f;
    uint4 brA[4], brB[4];
    uint2 mkA0, mkA1, mkB0, mkB1;
    short8 pa0[2], pa1[2];

#define LOADSET(br, mk0v, mk1v, c) do {                                      \
        _Pragma("unroll")                                                    \
        for (int k = 0; k < 4; ++k)                                          \
            br[k] = *(const uint4*)(gB[k] + (size_t)(c) * 64);               \
        mk0v = *(const uint2*)(mrow0 + (c) * 2);                             \
        mk1v = *(const uint2*)(mrow1 + (c) * 2);                             \
    } while (0)

#define STOREB(buf, br) do {                                                 \
        _Pragma("unroll")                                                    \
        for (int k = 0; k < 4; ++k)                                          \
            *(uint4*)&BsL[buf][ldsOff[k]] = br[k];                           \
    } while (0)

#define PCOMP(mk0v, mk1v, c) do {                                            \
        _Pragma("unroll")                                                    \
        for (int ks = 0; ks < 2; ++ks) {                                     \
            uint4 ea = *(const uint4*)&EGs[(c) * 64 + ks * 32 + fk * 8];     \
            uint4 eb = *(const uint4*)&EGs[(c) * 64 + ks * 32 + fk * 8 + 4]; \
            unsigned int egw[8];                                             \
            *(uint4*)&egw[0] = ea; *(uint4*)&egw[4] = eb;                    \
            unsigned int m0 = ((ks ? mk0v.y : mk0v.x) >> (fk * 8)) & 0xffu;  \
            unsigned int m1 = ((ks ? mk1v.y : mk1v.x) >> (fk * 8)) & 0xffu;  \
            _Pragma("unroll")                                                \
            for (int e = 0; e < 8; ++e) {                                    \
                float e2 = bf2f((unsigned short)(egw[e] & 0xffffu));         \
                float g2 = bf2f((unsigned short)(egw[e] >> 16));             \
                float w0 = fmaxf(e1_0 * e2, g1_0 * g2);                      \
                float w1 = fmaxf(e1_1 * e2, g1_1 * g2);                      \
                w0 = ((m0 >> e) & 1u) ? w0 : 0.f;                            \
                w1 = ((m1 >> e) & 1u) ? w1 : 0.f;                            \
                unsigned short bw0 = f2bf(w0), bw1 = f2bf(w1);               \
                pa0[ks][e] = (short)bw0;                                     \
                pa1[ks][e] = (short)bw1;                                     \
                sp0 += bf2f(bw0); sp1 += bf2f(bw1);                          \
            }                                                                \
        }                                                                    \
    } while (0)

#define MFMAC(buf) do {                                                      \
        _Pragma("unroll")                                                    \
        for (int ks = 0; ks < 2; ++ks) {                                     \
            const int rb = ks ? rb1 : rb0;                                   \
            _Pragma("unroll")                                                \
            for (int dtl = 0; dtl < 4; ++dtl) {                              \
                short8 bF = *(const short8*)                                 \
                    &BsL[buf][((wc * 4 + dtl) * 2 + ks) * 512 + rb];         \
                acc[0][dtl] = __builtin_amdgcn_mfma_f32_16x16x32_bf16(       \
                    pa0[ks], bF, acc[0][dtl], 0, 0, 0);                      \
                acc[1][dtl] = __builtin_amdgcn_mfma_f32_16x16x32_bf16(       \
                    pa1[ks], bF, acc[1][dtl], 0, 0, 0);                      \
            }                                                                \
        }                                                                    \
    } while (0)

    // prologue: chunk0 -> buf0; prefetch chunk1 -> regsB
    LOADSET(brA, mkA0, mkA1, 0);
    STOREB(0, brA);
    LOADSET(brB, mkB0, mkB1, 1);
    __syncthreads();

    #pragma unroll 1
    for (int cc = 0; cc < NC; cc += 2) {
        PCOMP(mkA0, mkA1, cc);
        STOREB(1, brB);                          // B of cc+1 -> buf1
        if (cc + 2 < NC) LOADSET(brA, mkA0, mkA1, cc + 2);
        MFMAC(0);                                // chunk cc from buf0
        __syncthreads();
        PCOMP(mkB0, mkB1, cc + 1);
        if (cc + 2 < NC) STOREB(0, brA);         // B of cc+2 -> buf0
        if (cc + 3 < NC) LOADSET(brB, mkB0, mkB1, cc + 3);
        MFMAC(1);                                // chunk cc+1 from buf1
        __syncthreads();
    }

#undef LOADSET
#undef STOREB
#undef PCOMP
#undef MFMAC

    // row sums: reduce over fk groups (stride 16, 32)
    sp0 += __shfl_xor(sp0, 16); sp0 += __shfl_xor(sp0, 32);
    sp1 += __shfl_xor(sp1, 16); sp1 += __shfl_xor(sp1, 32);
    if (wc == 0 && fk == 0) {
        Srow[wr * 32 + fr]      = sp0;
        Srow[wr * 32 + 16 + fr] = sp1;
    }
    __syncthreads();
    if (tid < 64) {
        if (DIRECT) Sred[tid] = 1.0f / Srow[tid];
        else        pS[(size_t)(b * S + split) * NN + i0 + tid] = Srow[tid];
    }
    __syncthreads();

    #pragma unroll
    for (int it = 0; it < 2; ++it) {
        #pragma unroll
        for (int dtl = 0; dtl < 4; ++dtl) {
            #pragma unroll
            for (int r = 0; r < 4; ++r) {
                const int i = wr * 32 + it * 16 + fk * 4 + r;
                const int d = wc * 64 + dtl * 16 + fr;
                const float av = acc[it][dtl][r];
                if (DIRECT) {
                    float hv = av * Sred[i];
                    hv = (hv > 0.f) ? hv : expm1f(hv);
                    out[((size_t)(b * NN) + i0 + i) * DD + d] = hv;
                } else {
                    pPV[((size_t)(b * S + split) * NN + i0 + i) * DD + d] = av;
                }
            }
        }
    }
}

// ---------------- Kernel D: combine splits, normalize, elu
template<int S>
__global__ __launch_bounds__(256) void reduce_kernel(
    const float* __restrict__ pPV, const float* __restrict__ pS,
    float* __restrict__ out)
{
    const int idx = blockIdx.x * 256 + threadIdx.x;
    const int bi = idx >> 5;
    const int d4 = (idx & 31) * 4;
    const int b  = bi >> 11;
    const int i  = bi & 2047;
    float4 sum = make_float4(0.f, 0.f, 0.f, 0.f);
    float ssum = 0.f;
    #pragma unroll
    for (int s = 0; s < S; ++s) {
        size_t base = (size_t)(b * S + s) * NN + i;
        float4 v = *(const float4*)&pPV[base * DD + d4];
        sum.x += v.x; sum.y += v.y; sum.z += v.z; sum.w += v.w;
        ssum  += pS[base];
    }
    float inv = 1.0f / ssum;
    float4 h;
    h.x = sum.x * inv; h.y = sum.y * inv; h.z = sum.z * inv; h.w = sum.w * inv;
    h.x = (h.x > 0.f) ? h.x : expm1f(h.x);
    h.y = (h.y > 0.f) ? h.y : expm1f(h.y);
    h.z = (h.z > 0.f) ? h.z : expm1f(h.z);
    h.w = (h.w > 0.f) ? h.w : expm1f(h.w);
    *(float4*)&out[(size_t)bi * DD + d4] = h;
}

extern "C" void kernel_launch(void* const* d_in, const int* in_sizes, int n_in,
                              void* d_out, int out_size, void* d_ws, size_t ws_size,
                              hipStream_t stream) {
    const float* x   = (const float*)d_in[0];
    const int*   adj = (const int*)d_in[1];
    const float* W   = (const float*)d_in[2];
    const float* a   = (const float*)d_in[3];
    float* out = (float*)d_out;

    char* p = (char*)d_ws;
    unsigned short* WhbT = (unsigned short*)p; p += (size_t)BB * NN * DD * 2;  // 4 MB
    float* f1 = (float*)p;          p += (size_t)BB * NN * 4;                  // 64 KB
    unsigned int* EGp = (unsigned int*)p; p += (size_t)BB * NN * 4;            // 64 KB
    unsigned short* Whi = (unsigned short*)p; p += (size_t)DD * CC * 2;        // 32 KB
    unsigned short* Wlo = (unsigned short*)p; p += (size_t)DD * CC * 2;        // 32 KB
    unsigned int* padj = (unsigned int*)p;    p += (size_t)NN * 64 * 4;        // 512 KB
    float* pPV = (float*)p;

    const size_t base_bytes = (size_t)(p - (char*)d_ws);
    const size_t per_split  = (size_t)BB * NN * DD * 4 + (size_t)BB * NN * 4;

    prep_kernel<<<PACK_BLOCKS + WSPL_BLOCKS, 256, 0, stream>>>(adj, padj, W, Whi, Wlo);
    wh_kernel<<<dim3(NN / 64, BB), 256, 0, stream>>>(x, Whi, Wlo, a, WhbT, f1, EGp);

    if (ws_size >= base_bytes + 2 * per_split) {
        constexpr int S = 2;
        float* pS = pPV + (size_t)S * BB * NN * DD;
        gat_kernel<S, false><<<dim3(NN / 64, S, BB), 256, 0, stream>>>(
            WhbT, padj, f1, EGp, out, pPV, pS);
        reduce_kernel<S><<<BB * NN * DD / 4 / 256, 256, 0, stream>>>(pPV, pS, out);
    } else {
        gat_kernel<1, true><<<dim3(NN / 64, 1, BB), 256, 0, stream>>>(
            WhbT, padj, f1, EGp, out, nullptr, nullptr);
    }
}

// Round 11
// 49.587 us; speedup vs baseline: 1.7002x; 1.7002x over previous
//
#include <hip/hip_runtime.h>
#include <hip/hip_bf16.h>
#include <math.h>

#define BB 8
#define NN 2048
#define CC 128
#define DD 128

typedef __attribute__((ext_vector_type(8))) short short8;
typedef __attribute__((ext_vector_type(4))) float f32x4;

static __device__ __forceinline__ unsigned short f2bf(float f) {
    __hip_bfloat16 h = __float2bfloat16(f);
    return *reinterpret_cast<unsigned short*>(&h);
}
static __device__ __forceinline__ float bf2f(unsigned short u) {
    __hip_bfloat16 h = *reinterpret_cast<__hip_bfloat16*>(&u);
    return __bfloat162float(h);
}

// ---------------- Kernel P: pack adj bitmask + split W hi/lo
#define PACK_BLOCKS (NN * NN / 256)          // 16384
#define WSPL_BLOCKS (DD * CC / 256)          // 64
__global__ __launch_bounds__(256) void prep_kernel(
    const int* __restrict__ adj, unsigned int* __restrict__ padj,
    const float* __restrict__ W,
    unsigned short* __restrict__ Whi, unsigned short* __restrict__ Wlo)
{
    const int bx  = blockIdx.x;
    const int tid = threadIdx.x;
    if (bx < PACK_BLOCKS) {
        const int idx  = bx * 256 + tid;
        const int i    = idx >> 11;
        const int j    = idx & 2047;
        const int lane = tid & 63;
        int ad = adj[(size_t)i * NN + j];
        unsigned long long m = __ballot(ad > 0);
        if (lane == 0)  padj[i * 64 + (j >> 5)] = (unsigned int)m;
        if (lane == 32) padj[i * 64 + (j >> 5)] = (unsigned int)(m >> 32);
    } else {
        const int g = (bx - PACK_BLOCKS) * 256 + tid;
        float w = W[g];
        unsigned short h = f2bf(w);
        Whi[g] = h;
        Wlo[g] = f2bf(w - bf2f(h));
    }
}

// ---------------- Kernel A: Wh = x @ W^T via compensated MFMA.
// Writes WhbT bf16 [b][d][n], f1 (raw), E2=exp(f2), G2=exp(0.2 f2).
__global__ __launch_bounds__(256) void wh_kernel(
    const float* __restrict__ x,
    const unsigned short* __restrict__ Whi, const unsigned short* __restrict__ Wlo,
    const float* __restrict__ a,
    unsigned short* __restrict__ WhbT,
    float* __restrict__ f1, float* __restrict__ E2g, float* __restrict__ G2g)
{
    const int tid  = threadIdx.x;
    const int b    = blockIdx.y;
    const int n0   = blockIdx.x * 64;
    const int w    = tid >> 6;
    const int lane = tid & 63;
    const int fr   = lane & 15, fk = lane >> 4;
    const int n    = n0 + w * 16 + fr;

    short8 bh[4], bl[4];
    const float* xrow = &x[((size_t)(b * NN) + n) * CC];
    #pragma unroll
    for (int ks = 0; ks < 4; ++ks) {
        float xv[8];
        *(float4*)&xv[0] = *(const float4*)&xrow[(ks * 4 + fk) * 8];
        *(float4*)&xv[4] = *(const float4*)&xrow[(ks * 4 + fk) * 8 + 4];
        #pragma unroll
        for (int e = 0; e < 8; ++e) {
            unsigned short h = f2bf(xv[e]);
            bh[ks][e] = (short)h;
            bl[ks][e] = (short)f2bf(xv[e] - bf2f(h));
        }
    }

    f32x4 acc[8];
    #pragma unroll
    for (int dt = 0; dt < 8; ++dt) acc[dt] = (f32x4){0.f, 0.f, 0.f, 0.f};

    #pragma unroll
    for (int dt = 0; dt < 8; ++dt) {
        #pragma unroll
        for (int ks = 0; ks < 4; ++ks) {
            const int off = (dt * 16 + fr) * CC + (ks * 4 + fk) * 8;
            short8 aH = *(const short8*)&Whi[off];
            short8 aL = *(const short8*)&Wlo[off];
            acc[dt] = __builtin_amdgcn_mfma_f32_16x16x32_bf16(aH, bh[ks], acc[dt], 0, 0, 0);
            acc[dt] = __builtin_amdgcn_mfma_f32_16x16x32_bf16(aH, bl[ks], acc[dt], 0, 0, 0);
            acc[dt] = __builtin_amdgcn_mfma_f32_16x16x32_bf16(aL, bh[ks], acc[dt], 0, 0, 0);
        }
    }

    float p1 = 0.f, p2 = 0.f;
    #pragma unroll
    for (int dt = 0; dt < 8; ++dt) {
        #pragma unroll
        for (int r = 0; r < 4; ++r) {
            const int d = dt * 16 + fk * 4 + r;
            p1 += acc[dt][r] * a[d];
            p2 += acc[dt][r] * a[DD + d];
        }
    }
    p1 += __shfl_xor(p1, 16); p1 += __shfl_xor(p1, 32);
    p2 += __shfl_xor(p2, 16); p2 += __shfl_xor(p2, 32);
    if (fk == 0) {
        f1[b * NN + n]  = p1;
        E2g[b * NN + n] = __expf(p2);
        G2g[b * NN + n] = __expf(0.2f * p2);
    }

    #pragma unroll
    for (int dt = 0; dt < 8; ++dt) {
        #pragma unroll
        for (int r = 0; r < 4; ++r) {
            const int d = dt * 16 + fk * 4 + r;
            WhbT[((size_t)(b * 128 + d)) * NN + n] = f2bf(acc[dt][r]);
        }
    }
}

// ---------------- Kernel C: MFMA attention (R7 structure), 64 i x 128 d, 8 waves.
// !DIRECT epilogue writes FRAGMENT-LINEAR float4 partials (full-line coalesced).
template<int S, bool DIRECT>
__global__ __launch_bounds__(512) void gat_kernel(
    const unsigned short* __restrict__ WhbT,   // [b][128 d][2048 n] bf16
    const unsigned int* __restrict__ padj,     // [2048][64] bitmask
    const float* __restrict__ f1,
    const float* __restrict__ E2g, const float* __restrict__ G2g,
    float* __restrict__ out,
    float* __restrict__ pPV, float* __restrict__ pS)
{
    constexpr int JS = NN / S;
    constexpr int NC = JS / 64;
    __shared__ __align__(16) unsigned short Bs[128 * 64];  // 16 KB
    __shared__ __align__(16) unsigned short Ps[64 * 64];   // 8 KB
    __shared__ float E2s[JS];
    __shared__ float G2s[JS];
    __shared__ float Srow[64];
    __shared__ float Sred[64];

    const int tid   = threadIdx.x;
    const int i0    = blockIdx.x * 64;
    const int split = blockIdx.y;
    const int b     = blockIdx.z;
    const int jBeg  = split * JS;

    #pragma unroll
    for (int k = 0; k < JS / 512; ++k) {
        E2s[tid + 512 * k] = E2g[b * NN + jBeg + tid + 512 * k];
        G2s[tid + 512 * k] = G2g[b * NN + jBeg + tid + 512 * k];
    }

    // P role: row = tid>>3 (64 rows), 8 j-elems at pjb*8
    const int prow = tid >> 3;
    const int pjb  = tid & 7;
    const float f1r = f1[b * NN + i0 + prow];
    const float E1r = __expf(f1r);
    const float G1r = __expf(0.2f * f1r);
    const int psw = ((pjb ^ (prow & 7)) << 3);
    const unsigned int* padjRow = padj + (size_t)(i0 + prow) * 64 + (jBeg >> 5);

    // MFMA role: wave (wr,wc) in 2x4
    const int w    = tid >> 6;
    const int wr   = w >> 2, wc = w & 3;
    const int lane = tid & 63;
    const int fr   = lane & 15;
    const int fk   = lane >> 4;
    f32x4 acc00 = {0.f,0.f,0.f,0.f}, acc01 = {0.f,0.f,0.f,0.f};
    f32x4 acc10 = {0.f,0.f,0.f,0.f}, acc11 = {0.f,0.f,0.f,0.f};
    float s_part = 0.f;

    // B staging: 1024 x 16B loads, 2 per thread
    const size_t wbase = (size_t)b * 128 * NN;
    const int g0 = tid,       gd0 = g0 >> 3, gj0 = (g0 & 7) * 8;
    const int g1 = tid + 512, gd1 = g1 >> 3, gj1 = (g1 & 7) * 8;
    const int sw0 = gd0 * 64 + ((((g0) & 7) ^ (gd0 & 7)) << 3);
    const int sw1 = gd1 * 64 + ((((g1) & 7) ^ (gd1 & 7)) << 3);

    // prefetch chunk 0
    uint4 br0 = *(const uint4*)&WhbT[wbase + (size_t)gd0 * NN + jBeg + gj0];
    uint4 br1 = *(const uint4*)&WhbT[wbase + (size_t)gd1 * NN + jBeg + gj1];
    unsigned int pw = padjRow[pjb >> 2];

    __syncthreads();   // E2s/G2s ready

    for (int c = 0; c < NC; ++c) {
        // (B) P chunk: w = max(E1*E2, G1*G2), masked by bit
        float4 eA = *(const float4*)&E2s[c * 64 + pjb * 8];
        float4 eB = *(const float4*)&E2s[c * 64 + pjb * 8 + 4];
        float4 gA = *(const float4*)&G2s[c * 64 + pjb * 8];
        float4 gB = *(const float4*)&G2s[c * 64 + pjb * 8 + 4];
        float ev[8], gv[8];
        *(float4*)&ev[0] = eA; *(float4*)&ev[4] = eB;
        *(float4*)&gv[0] = gA; *(float4*)&gv[4] = gB;
        unsigned int pbits = (pw >> ((pjb & 3) << 3)) & 0xffu;
        unsigned short pks[8];
        float ssum = 0.f;
        #pragma unroll
        for (int e = 0; e < 8; ++e) {
            float m  = E1r * ev[e];
            float g  = G1r * gv[e];
            float wv = fmaxf(m, g);
            wv = ((pbits >> e) & 1u) ? wv : 0.f;
            unsigned short bw = f2bf(wv);
            pks[e] = bw;
            ssum += bf2f(bw);
        }
        s_part += ssum;

        if (c > 0) __syncthreads();   // prev MFMA done reading LDS
        // (C) LDS writes
        *(uint4*)&Bs[sw0] = br0;
        *(uint4*)&Bs[sw1] = br1;
        {
            uint4 pv;
            pv.x = (unsigned int)pks[0] | ((unsigned int)pks[1] << 16);
            pv.y = (unsigned int)pks[2] | ((unsigned int)pks[3] << 16);
            pv.z = (unsigned int)pks[4] | ((unsigned int)pks[5] << 16);
            pv.w = (unsigned int)pks[6] | ((unsigned int)pks[7] << 16);
            *(uint4*)&Ps[prow * 64 + psw] = pv;
        }
        // (A) prefetch next chunk
        if (c + 1 < NC) {
            const int j0n = jBeg + (c + 1) * 64;
            br0 = *(const uint4*)&WhbT[wbase + (size_t)gd0 * NN + j0n + gj0];
            br1 = *(const uint4*)&WhbT[wbase + (size_t)gd1 * NN + j0n + gj1];
            pw  = padjRow[(c + 1) * 2 + (pjb >> 2)];
        }
        __syncthreads();   // tiles ready
        // (D) MFMA (A-rows offset by wr*32 — the R10 bug was dropping this)
        __builtin_amdgcn_s_setprio(1);
        #pragma unroll
        for (int ks = 0; ks < 2; ++ks) {
            const int jbl = ks * 4 + fk;
            const int sb  = ((jbl ^ (fr & 7)) << 3);
            short8 aF0 = *(const short8*)&Ps[(wr * 32 + fr) * 64 + sb];
            short8 aF1 = *(const short8*)&Ps[(wr * 32 + 16 + fr) * 64 + sb];
            short8 bF0 = *(const short8*)&Bs[(wc * 32 + fr) * 64 + sb];
            short8 bF1 = *(const short8*)&Bs[(wc * 32 + 16 + fr) * 64 + sb];
            acc00 = __builtin_amdgcn_mfma_f32_16x16x32_bf16(aF0, bF0, acc00, 0, 0, 0);
            acc01 = __builtin_amdgcn_mfma_f32_16x16x32_bf16(aF0, bF1, acc01, 0, 0, 0);
            acc10 = __builtin_amdgcn_mfma_f32_16x16x32_bf16(aF1, bF0, acc10, 0, 0, 0);
            acc11 = __builtin_amdgcn_mfma_f32_16x16x32_bf16(aF1, bF1, acc11, 0, 0, 0);
        }
        __builtin_amdgcn_s_setprio(0);
    }

    // row-sum: 8 threads per row
    {
        float v = s_part;
        v += __shfl_xor(v, 1); v += __shfl_xor(v, 2); v += __shfl_xor(v, 4);
        if (pjb == 0) Srow[prow] = v;
    }
    __syncthreads();
    if (tid < 64) {
        float st = Srow[tid];
        if (DIRECT) Sred[tid] = 1.0f / st;
        else        pS[(size_t)(b * S + split) * NN + i0 + tid] = st;
    }
    __syncthreads();

    if (DIRECT) {
        #pragma unroll
        for (int it = 0; it < 2; ++it) {
            #pragma unroll
            for (int dt = 0; dt < 2; ++dt) {
                f32x4 av = (it == 0) ? (dt == 0 ? acc00 : acc01)
                                     : (dt == 0 ? acc10 : acc11);
                #pragma unroll
                for (int r = 0; r < 4; ++r) {
                    int i = wr * 32 + it * 16 + fk * 4 + r;
                    int d = wc * 32 + dt * 16 + fr;
                    float hv = av[r] * Sred[i];
                    hv = (hv > 0.f) ? hv : expm1f(hv);
                    out[((size_t)(b * NN) + i0 + i) * DD + d] = hv;
                }
            }
        }
    } else {
        // fragment-linear partials: chunk = [(b*S+split)*32 + i0blk] * 8192 floats.
        // Store q-th f32x4 at (q*512 + tid)*4 -> each store = 64 lanes x 16 B contiguous.
        float* pbase = pPV + ((size_t)(b * S + split) * (NN / 64) + blockIdx.x) * 8192;
        *(f32x4*)&pbase[(0 * 512 + tid) * 4] = acc00;
        *(f32x4*)&pbase[(1 * 512 + tid) * 4] = acc01;
        *(f32x4*)&pbase[(2 * 512 + tid) * 4] = acc10;
        *(f32x4*)&pbase[(3 * 512 + tid) * 4] = acc11;
    }
}

// ---------------- Kernel D: combine fragment-linear splits, normalize, elu,
// LDS-transpose, coalesced float4 out. One block per (i0blk, b).
template<int S>
__global__ __launch_bounds__(512) void reduce_kernel(
    const float* __restrict__ pPV, const float* __restrict__ pS,
    float* __restrict__ out)
{
    __shared__ float T[64 * 132];   // 33.8 KB
    __shared__ float Sred[64];

    const int tid   = threadIdx.x;
    const int i0blk = blockIdx.x;
    const int b     = blockIdx.y;
    const int i0    = i0blk * 64;

    if (tid < 64) {
        float st = 0.f;
        #pragma unroll
        for (int s = 0; s < S; ++s)
            st += pS[(size_t)(b * S + s) * NN + i0 + tid];
        Sred[tid] = 1.0f / st;
    }
    __syncthreads();

    const int w    = tid >> 6;
    const int wr   = w >> 2, wc = w & 3;
    const int lane = tid & 63;
    const int fr   = lane & 15, fk = lane >> 4;

    #pragma unroll
    for (int q = 0; q < 4; ++q) {
        f32x4 sum = {0.f, 0.f, 0.f, 0.f};
        #pragma unroll
        for (int s = 0; s < S; ++s) {
            const float* pbase = pPV +
                ((size_t)(b * S + s) * (NN / 64) + i0blk) * 8192;
            f32x4 v = *(const f32x4*)&pbase[(q * 512 + tid) * 4];
            sum[0] += v[0]; sum[1] += v[1]; sum[2] += v[2]; sum[3] += v[3];
        }
        const int it = q >> 1, dt = q & 1;
        #pragma unroll
        for (int r = 0; r < 4; ++r) {
            const int i = wr * 32 + it * 16 + fk * 4 + r;
            const int d = wc * 32 + dt * 16 + fr;
            float hv = sum[r] * Sred[i];
            hv = (hv > 0.f) ? hv : expm1f(hv);
            T[i * 132 + d] = hv;
        }
    }
    __syncthreads();

    #pragma unroll
    for (int k = 0; k < 4; ++k) {
        const int g   = tid + 512 * k;     // 2048 float4 = 64 x 128
        const int row = g >> 5;
        const int d4  = (g & 31) * 4;
        float4 h = *(const float4*)&T[row * 132 + d4];
        *(float4*)&out[((size_t)(b * NN) + i0 + row) * DD + d4] = h;
    }
}

extern "C" void kernel_launch(void* const* d_in, const int* in_sizes, int n_in,
                              void* d_out, int out_size, void* d_ws, size_t ws_size,
                              hipStream_t stream) {
    const float* x   = (const float*)d_in[0];
    const int*   adj = (const int*)d_in[1];
    const float* W   = (const float*)d_in[2];
    const float* a   = (const float*)d_in[3];
    float* out = (float*)d_out;

    char* p = (char*)d_ws;
    unsigned short* WhbT = (unsigned short*)p; p += (size_t)BB * NN * DD * 2;  // 4 MB
    float* f1  = (float*)p; p += (size_t)BB * NN * 4;                          // 64 KB
    float* E2g = (float*)p; p += (size_t)BB * NN * 4;                          // 64 KB
    float* G2g = (float*)p; p += (size_t)BB * NN * 4;                          // 64 KB
    unsigned short* Whi = (unsigned short*)p; p += (size_t)DD * CC * 2;        // 32 KB
    unsigned short* Wlo = (unsigned short*)p; p += (size_t)DD * CC * 2;        // 32 KB
    unsigned int* padj = (unsigned int*)p;    p += (size_t)NN * 64 * 4;        // 512 KB
    float* pPV = (float*)p;

    const size_t base_bytes = (size_t)(p - (char*)d_ws);
    const size_t per_split  = (size_t)BB * NN * DD * 4 + (size_t)BB * NN * 4;

    prep_kernel<<<PACK_BLOCKS + WSPL_BLOCKS, 256, 0, stream>>>(adj, padj, W, Whi, Wlo);
    wh_kernel<<<dim3(NN / 64, BB), 256, 0, stream>>>(x, Whi, Wlo, a, WhbT, f1, E2g, G2g);

    if (ws_size >= base_bytes + 2 * per_split) {
        constexpr int S = 2;
        float* pS = pPV + (size_t)S * BB * NN * DD;
        gat_kernel<S, false><<<dim3(NN / 64, S, BB), 512, 0, stream>>>(
            WhbT, padj, f1, E2g, G2g, out, pPV, pS);
        reduce_kernel<S><<<dim3(NN / 64, BB), 512, 0, stream>>>(pPV, pS, out);
    } else {
        gat_kernel<1, true><<<dim3(NN / 64, 1, BB), 512, 0, stream>>>(
            WhbT, padj, f1, E2g, G2g, out, nullptr, nullptr);
    }
}

// Round 12
// 39.085 us; speedup vs baseline: 2.1570x; 1.2687x over previous
//
#include <hip/hip_runtime.h>
#include <hip/hip_bf16.h>
#include <math.h>

#define BB 8
#define NN 2048
#define CC 128
#define DD 128

typedef __attribute__((ext_vector_type(8))) short short8;
typedef __attribute__((ext_vector_type(4))) float f32x4;

static __device__ __forceinline__ unsigned short f2bf(float f) {
    __hip_bfloat16 h = __float2bfloat16(f);
    return *reinterpret_cast<unsigned short*>(&h);
}
static __device__ __forceinline__ float bf2f(unsigned short u) {
    __hip_bfloat16 h = *reinterpret_cast<__hip_bfloat16*>(&u);
    return __bfloat162float(h);
}

// ---------------- Kernel A: fused adj-pack (blocks 0..255) + Wh compute (blocks 256..511).
// Pack: thread computes 2 bitmask words from 32 ints each (no cross-lane).
// Wh: W split to bf16 hi/lo in LDS per block; compensated MFMA; writes WhbT bf16
//     [b][d][n], f1, E2=exp(f2), G2=exp(0.2 f2). XCD-swizzled: batch = (bx-256)&7.
#define PACKB 256
__global__ __launch_bounds__(256) void prep_wh_kernel(
    const int* __restrict__ adj, unsigned int* __restrict__ padj,
    const float* __restrict__ x, const float* __restrict__ W,
    const float* __restrict__ a,
    unsigned short* __restrict__ WhbT,
    float* __restrict__ f1, float* __restrict__ E2g, float* __restrict__ G2g)
{
    __shared__ unsigned short Whs[128 * 136];   // 34.8 KB
    __shared__ unsigned short Wls[128 * 136];   // 34.8 KB
    const int bx  = blockIdx.x;
    const int tid = threadIdx.x;

    if (bx < PACKB) {
        // ---- adj bitmask pack: 131072 words, 2 per thread
        const int wid = bx * 256 + tid;          // 0..65535
        #pragma unroll
        for (int rep = 0; rep < 2; ++rep) {
            const int word = wid + rep * 65536;
            const int4* src = (const int4*)adj + (size_t)word * 8;
            unsigned int m = 0;
            #pragma unroll
            for (int k = 0; k < 8; ++k) {
                int4 v = src[k];
                m |= (v.x > 0 ? 1u : 0u) << (k * 4);
                m |= (v.y > 0 ? 1u : 0u) << (k * 4 + 1);
                m |= (v.z > 0 ? 1u : 0u) << (k * 4 + 2);
                m |= (v.w > 0 ? 1u : 0u) << (k * 4 + 3);
            }
            padj[word] = m;
        }
        return;
    }

    // ---- Wh part
    const int g  = bx - PACKB;
    const int b  = g & 7;            // XCD-locality: batch b -> XCD b
    const int n0 = (g >> 3) * 64;

    // stage + split W (16384 f32) into LDS
    #pragma unroll
    for (int k = 0; k < 16; ++k) {
        const int e   = tid + 256 * k;       // float4 index
        float4 wv = *(const float4*)&W[e * 4];
        const int row = e >> 5;
        const int col = (e & 31) * 4;
        ushort4 hv, lv;
        hv.x = f2bf(wv.x); lv.x = f2bf(wv.x - bf2f(hv.x));
        hv.y = f2bf(wv.y); lv.y = f2bf(wv.y - bf2f(hv.y));
        hv.z = f2bf(wv.z); lv.z = f2bf(wv.z - bf2f(hv.z));
        hv.w = f2bf(wv.w); lv.w = f2bf(wv.w - bf2f(hv.w));
        *(ushort4*)&Whs[row * 136 + col] = hv;
        *(ushort4*)&Wls[row * 136 + col] = lv;
    }
    __syncthreads();

    const int w    = tid >> 6;
    const int lane = tid & 63;
    const int fr   = lane & 15, fk = lane >> 4;
    const int n    = n0 + w * 16 + fr;

    short8 bh[4], bl[4];
    const float* xrow = &x[((size_t)(b * NN) + n) * CC];
    #pragma unroll
    for (int ks = 0; ks < 4; ++ks) {
        float xv[8];
        *(float4*)&xv[0] = *(const float4*)&xrow[(ks * 4 + fk) * 8];
        *(float4*)&xv[4] = *(const float4*)&xrow[(ks * 4 + fk) * 8 + 4];
        #pragma unroll
        for (int e = 0; e < 8; ++e) {
            unsigned short h = f2bf(xv[e]);
            bh[ks][e] = (short)h;
            bl[ks][e] = (short)f2bf(xv[e] - bf2f(h));
        }
    }

    f32x4 acc[8];
    #pragma unroll
    for (int dt = 0; dt < 8; ++dt) acc[dt] = (f32x4){0.f, 0.f, 0.f, 0.f};

    #pragma unroll
    for (int dt = 0; dt < 8; ++dt) {
        #pragma unroll
        for (int ks = 0; ks < 4; ++ks) {
            const int off = (dt * 16 + fr) * 136 + (ks * 4 + fk) * 8;
            short8 aH = *(const short8*)&Whs[off];
            short8 aL = *(const short8*)&Wls[off];
            acc[dt] = __builtin_amdgcn_mfma_f32_16x16x32_bf16(aH, bh[ks], acc[dt], 0, 0, 0);
            acc[dt] = __builtin_amdgcn_mfma_f32_16x16x32_bf16(aH, bl[ks], acc[dt], 0, 0, 0);
            acc[dt] = __builtin_amdgcn_mfma_f32_16x16x32_bf16(aL, bh[ks], acc[dt], 0, 0, 0);
        }
    }

    float p1 = 0.f, p2 = 0.f;
    #pragma unroll
    for (int dt = 0; dt < 8; ++dt) {
        #pragma unroll
        for (int r = 0; r < 4; ++r) {
            const int d = dt * 16 + fk * 4 + r;
            p1 += acc[dt][r] * a[d];
            p2 += acc[dt][r] * a[DD + d];
        }
    }
    p1 += __shfl_xor(p1, 16); p1 += __shfl_xor(p1, 32);
    p2 += __shfl_xor(p2, 16); p2 += __shfl_xor(p2, 32);
    if (fk == 0) {
        f1[b * NN + n]  = p1;
        E2g[b * NN + n] = __expf(p2);
        G2g[b * NN + n] = __expf(0.2f * p2);
    }

    #pragma unroll
    for (int dt = 0; dt < 8; ++dt) {
        #pragma unroll
        for (int r = 0; r < 4; ++r) {
            const int d = dt * 16 + fk * 4 + r;
            WhbT[((size_t)(b * 128 + d)) * NN + n] = f2bf(acc[dt][r]);
        }
    }
}

// ---------------- Kernel C: MFMA attention (R11 structure, passing), flat grid,
// XCD-swizzled: b = blockIdx.x & 7 so each XCD streams only its batch's WhbT from L2.
template<int S, bool DIRECT>
__global__ __launch_bounds__(512) void gat_kernel(
    const unsigned short* __restrict__ WhbT,   // [b][128 d][2048 n] bf16
    const unsigned int* __restrict__ padj,     // [2048][64] bitmask
    const float* __restrict__ f1,
    const float* __restrict__ E2g, const float* __restrict__ G2g,
    float* __restrict__ out,
    float* __restrict__ pPV, float* __restrict__ pS)
{
    constexpr int JS = NN / S;
    constexpr int NC = JS / 64;
    __shared__ __align__(16) unsigned short Bs[128 * 64];  // 16 KB
    __shared__ __align__(16) unsigned short Ps[64 * 64];   // 8 KB
    __shared__ float E2s[JS];
    __shared__ float G2s[JS];
    __shared__ float Srow[64];
    __shared__ float Sred[64];

    const int tid   = threadIdx.x;
    const int gblk  = blockIdx.x;
    const int b     = gblk & 7;          // XCD-locality
    const int rdec  = gblk >> 3;
    const int i0blk = rdec & 31;
    const int split = rdec >> 5;
    const int i0    = i0blk * 64;
    const int jBeg  = split * JS;

    #pragma unroll
    for (int k = 0; k < JS / 512; ++k) {
        E2s[tid + 512 * k] = E2g[b * NN + jBeg + tid + 512 * k];
        G2s[tid + 512 * k] = G2g[b * NN + jBeg + tid + 512 * k];
    }

    // P role: row = tid>>3 (64 rows), 8 j-elems at pjb*8
    const int prow = tid >> 3;
    const int pjb  = tid & 7;
    const float f1r = f1[b * NN + i0 + prow];
    const float E1r = __expf(f1r);
    const float G1r = __expf(0.2f * f1r);
    const int psw = ((pjb ^ (prow & 7)) << 3);
    const unsigned int* padjRow = padj + (size_t)(i0 + prow) * 64 + (jBeg >> 5);

    // MFMA role: wave (wr,wc) in 2x4
    const int w    = tid >> 6;
    const int wr   = w >> 2, wc = w & 3;
    const int lane = tid & 63;
    const int fr   = lane & 15;
    const int fk   = lane >> 4;
    f32x4 acc00 = {0.f,0.f,0.f,0.f}, acc01 = {0.f,0.f,0.f,0.f};
    f32x4 acc10 = {0.f,0.f,0.f,0.f}, acc11 = {0.f,0.f,0.f,0.f};
    float s_part = 0.f;

    // B staging: 1024 x 16B loads, 2 per thread
    const size_t wbase = (size_t)b * 128 * NN;
    const int g0 = tid,       gd0 = g0 >> 3, gj0 = (g0 & 7) * 8;
    const int g1 = tid + 512, gd1 = g1 >> 3, gj1 = (g1 & 7) * 8;
    const int sw0 = gd0 * 64 + ((((g0) & 7) ^ (gd0 & 7)) << 3);
    const int sw1 = gd1 * 64 + ((((g1) & 7) ^ (gd1 & 7)) << 3);

    // prefetch chunk 0
    uint4 br0 = *(const uint4*)&WhbT[wbase + (size_t)gd0 * NN + jBeg + gj0];
    uint4 br1 = *(const uint4*)&WhbT[wbase + (size_t)gd1 * NN + jBeg + gj1];
    unsigned int pw = padjRow[pjb >> 2];

    __syncthreads();   // E2s/G2s ready

    for (int c = 0; c < NC; ++c) {
        // (B) P chunk: w = max(E1*E2, G1*G2), masked by bit
        float4 eA = *(const float4*)&E2s[c * 64 + pjb * 8];
        float4 eB = *(const float4*)&E2s[c * 64 + pjb * 8 + 4];
        float4 gA = *(const float4*)&G2s[c * 64 + pjb * 8];
        float4 gB = *(const float4*)&G2s[c * 64 + pjb * 8 + 4];
        float ev[8], gv[8];
        *(float4*)&ev[0] = eA; *(float4*)&ev[4] = eB;
        *(float4*)&gv[0] = gA; *(float4*)&gv[4] = gB;
        unsigned int pbits = (pw >> ((pjb & 3) << 3)) & 0xffu;
        unsigned short pks[8];
        float ssum = 0.f;
        #pragma unroll
        for (int e = 0; e < 8; ++e) {
            float m  = E1r * ev[e];
            float g  = G1r * gv[e];
            float wv = fmaxf(m, g);
            wv = ((pbits >> e) & 1u) ? wv : 0.f;
            unsigned short bw = f2bf(wv);
            pks[e] = bw;
            ssum += bf2f(bw);
        }
        s_part += ssum;

        if (c > 0) __syncthreads();   // prev MFMA done reading LDS
        // (C) LDS writes
        *(uint4*)&Bs[sw0] = br0;
        *(uint4*)&Bs[sw1] = br1;
        {
            uint4 pv;
            pv.x = (unsigned int)pks[0] | ((unsigned int)pks[1] << 16);
            pv.y = (unsigned int)pks[2] | ((unsigned int)pks[3] << 16);
            pv.z = (unsigned int)pks[4] | ((unsigned int)pks[5] << 16);
            pv.w = (unsigned int)pks[6] | ((unsigned int)pks[7] << 16);
            *(uint4*)&Ps[prow * 64 + psw] = pv;
        }
        // (A) prefetch next chunk
        if (c + 1 < NC) {
            const int j0n = jBeg + (c + 1) * 64;
            br0 = *(const uint4*)&WhbT[wbase + (size_t)gd0 * NN + j0n + gj0];
            br1 = *(const uint4*)&WhbT[wbase + (size_t)gd1 * NN + j0n + gj1];
            pw  = padjRow[(c + 1) * 2 + (pjb >> 2)];
        }
        __syncthreads();   // tiles ready
        // (D) MFMA
        __builtin_amdgcn_s_setprio(1);
        #pragma unroll
        for (int ks = 0; ks < 2; ++ks) {
            const int jbl = ks * 4 + fk;
            const int sb  = ((jbl ^ (fr & 7)) << 3);
            short8 aF0 = *(const short8*)&Ps[(wr * 32 + fr) * 64 + sb];
            short8 aF1 = *(const short8*)&Ps[(wr * 32 + 16 + fr) * 64 + sb];
            short8 bF0 = *(const short8*)&Bs[(wc * 32 + fr) * 64 + sb];
            short8 bF1 = *(const short8*)&Bs[(wc * 32 + 16 + fr) * 64 + sb];
            acc00 = __builtin_amdgcn_mfma_f32_16x16x32_bf16(aF0, bF0, acc00, 0, 0, 0);
            acc01 = __builtin_amdgcn_mfma_f32_16x16x32_bf16(aF0, bF1, acc01, 0, 0, 0);
            acc10 = __builtin_amdgcn_mfma_f32_16x16x32_bf16(aF1, bF0, acc10, 0, 0, 0);
            acc11 = __builtin_amdgcn_mfma_f32_16x16x32_bf16(aF1, bF1, acc11, 0, 0, 0);
        }
        __builtin_amdgcn_s_setprio(0);
    }

    // row-sum: 8 threads per row
    {
        float v = s_part;
        v += __shfl_xor(v, 1); v += __shfl_xor(v, 2); v += __shfl_xor(v, 4);
        if (pjb == 0) Srow[prow] = v;
    }
    __syncthreads();
    if (tid < 64) {
        float st = Srow[tid];
        if (DIRECT) Sred[tid] = 1.0f / st;
        else        pS[(size_t)(b * S + split) * NN + i0 + tid] = st;
    }
    __syncthreads();

    if (DIRECT) {
        #pragma unroll
        for (int it = 0; it < 2; ++it) {
            #pragma unroll
            for (int dt = 0; dt < 2; ++dt) {
                f32x4 av = (it == 0) ? (dt == 0 ? acc00 : acc01)
                                     : (dt == 0 ? acc10 : acc11);
                #pragma unroll
                for (int r = 0; r < 4; ++r) {
                    int i = wr * 32 + it * 16 + fk * 4 + r;
                    int d = wc * 32 + dt * 16 + fr;
                    float hv = av[r] * Sred[i];
                    hv = (hv > 0.f) ? hv : expm1f(hv);
                    out[((size_t)(b * NN) + i0 + i) * DD + d] = hv;
                }
            }
        }
    } else {
        // fragment-linear partials (full-line coalesced)
        float* pbase = pPV + ((size_t)(b * S + split) * (NN / 64) + i0blk) * 8192;
        *(f32x4*)&pbase[(0 * 512 + tid) * 4] = acc00;
        *(f32x4*)&pbase[(1 * 512 + tid) * 4] = acc01;
        *(f32x4*)&pbase[(2 * 512 + tid) * 4] = acc10;
        *(f32x4*)&pbase[(3 * 512 + tid) * 4] = acc11;
    }
}

// ---------------- Kernel D: combine fragment-linear splits, normalize, elu,
// LDS-transpose, coalesced float4 out. Flat grid, XCD-matched to gat writers.
template<int S>
__global__ __launch_bounds__(512) void reduce_kernel(
    const float* __restrict__ pPV, const float* __restrict__ pS,
    float* __restrict__ out)
{
    __shared__ float T[64 * 132];   // 33.8 KB
    __shared__ float Sred[64];

    const int tid   = threadIdx.x;
    const int gblk  = blockIdx.x;
    const int b     = gblk & 7;          // same XCD as the gat blocks that wrote batch b
    const int i0blk = gblk >> 3;
    const int i0    = i0blk * 64;

    if (tid < 64) {
        float st = 0.f;
        #pragma unroll
        for (int s = 0; s < S; ++s)
            st += pS[(size_t)(b * S + s) * NN + i0 + tid];
        Sred[tid] = 1.0f / st;
    }
    __syncthreads();

    const int w    = tid >> 6;
    const int wr   = w >> 2, wc = w & 3;
    const int lane = tid & 63;
    const int fr   = lane & 15, fk = lane >> 4;

    #pragma unroll
    for (int q = 0; q < 4; ++q) {
        f32x4 sum = {0.f, 0.f, 0.f, 0.f};
        #pragma unroll
        for (int s = 0; s < S; ++s) {
            const float* pbase = pPV +
                ((size_t)(b * S + s) * (NN / 64) + i0blk) * 8192;
            f32x4 v = *(const f32x4*)&pbase[(q * 512 + tid) * 4];
            sum[0] += v[0]; sum[1] += v[1]; sum[2] += v[2]; sum[3] += v[3];
        }
        const int it = q >> 1, dt = q & 1;
        #pragma unroll
        for (int r = 0; r < 4; ++r) {
            const int i = wr * 32 + it * 16 + fk * 4 + r;
            const int d = wc * 32 + dt * 16 + fr;
            float hv = sum[r] * Sred[i];
            hv = (hv > 0.f) ? hv : expm1f(hv);
            T[i * 132 + d] = hv;
        }
    }
    __syncthreads();

    #pragma unroll
    for (int k = 0; k < 4; ++k) {
        const int g   = tid + 512 * k;     // 2048 float4 = 64 x 128
        const int row = g >> 5;
        const int d4  = (g & 31) * 4;
        float4 h = *(const float4*)&T[row * 132 + d4];
        *(float4*)&out[((size_t)(b * NN) + i0 + row) * DD + d4] = h;
    }
}

extern "C" void kernel_launch(void* const* d_in, const int* in_sizes, int n_in,
                              void* d_out, int out_size, void* d_ws, size_t ws_size,
                              hipStream_t stream) {
    const float* x   = (const float*)d_in[0];
    const int*   adj = (const int*)d_in[1];
    const float* W   = (const float*)d_in[2];
    const float* a   = (const float*)d_in[3];
    float* out = (float*)d_out;

    char* p = (char*)d_ws;
    unsigned short* WhbT = (unsigned short*)p; p += (size_t)BB * NN * DD * 2;  // 4 MB
    float* f1  = (float*)p; p += (size_t)BB * NN * 4;                          // 64 KB
    float* E2g = (float*)p; p += (size_t)BB * NN * 4;                          // 64 KB
    float* G2g = (float*)p; p += (size_t)BB * NN * 4;                          // 64 KB
    unsigned int* padj = (unsigned int*)p;    p += (size_t)NN * 64 * 4;        // 512 KB
    float* pPV = (float*)p;

    const size_t base_bytes = (size_t)(p - (char*)d_ws);
    const size_t per_split  = (size_t)BB * NN * DD * 4 + (size_t)BB * NN * 4;

    prep_wh_kernel<<<PACKB + (NN / 64) * BB, 256, 0, stream>>>(
        adj, padj, x, W, a, WhbT, f1, E2g, G2g);

    if (ws_size >= base_bytes + 2 * per_split) {
        constexpr int S = 2;
        float* pS = pPV + (size_t)S * BB * NN * DD;
        gat_kernel<S, false><<<(NN / 64) * S * BB, 512, 0, stream>>>(
            WhbT, padj, f1, E2g, G2g, out, pPV, pS);
        reduce_kernel<S><<<(NN / 64) * BB, 512, 0, stream>>>(pPV, pS, out);
    } else {
        gat_kernel<1, true><<<(NN / 64) * BB, 512, 0, stream>>>(
            WhbT, padj, f1, E2g, G2g, out, nullptr, nullptr);
    }
}

// Round 13
// 37.022 us; speedup vs baseline: 2.2772x; 1.0557x over previous
//
#include <hip/hip_runtime.h>
#include <hip/hip_bf16.h>
#include <math.h>

#define BB 8
#define NN 2048
#define CC 128
#define DD 128

typedef __attribute__((ext_vector_type(8))) short short8;
typedef __attribute__((ext_vector_type(4))) float f32x4;

static __device__ __forceinline__ unsigned short f2bf(float f) {
    __hip_bfloat16 h = __float2bfloat16(f);
    return *reinterpret_cast<unsigned short*>(&h);
}
static __device__ __forceinline__ float bf2f(unsigned short u) {
    __hip_bfloat16 h = *reinterpret_cast<__hip_bfloat16*>(&u);
    return __bfloat162float(h);
}

// ---------------- Kernel A: fused adj-pack (blocks 0..255) + Wh compute (256..511).
#define PACKB 256
__global__ __launch_bounds__(256) void prep_wh_kernel(
    const int* __restrict__ adj, unsigned int* __restrict__ padj,
    const float* __restrict__ x, const float* __restrict__ W,
    const float* __restrict__ a,
    unsigned short* __restrict__ WhbT,
    float* __restrict__ f1, float* __restrict__ E2g, float* __restrict__ G2g)
{
    __shared__ unsigned short Whs[128 * 136];
    __shared__ unsigned short Wls[128 * 136];
    const int bx  = blockIdx.x;
    const int tid = threadIdx.x;

    if (bx < PACKB) {
        const int wid = bx * 256 + tid;
        #pragma unroll
        for (int rep = 0; rep < 2; ++rep) {
            const int word = wid + rep * 65536;
            const int4* src = (const int4*)adj + (size_t)word * 8;
            unsigned int m = 0;
            #pragma unroll
            for (int k = 0; k < 8; ++k) {
                int4 v = src[k];
                m |= (v.x > 0 ? 1u : 0u) << (k * 4);
                m |= (v.y > 0 ? 1u : 0u) << (k * 4 + 1);
                m |= (v.z > 0 ? 1u : 0u) << (k * 4 + 2);
                m |= (v.w > 0 ? 1u : 0u) << (k * 4 + 3);
            }
            padj[word] = m;
        }
        return;
    }

    const int g  = bx - PACKB;
    const int b  = g & 7;            // XCD-locality: batch b -> XCD b
    const int n0 = (g >> 3) * 64;

    #pragma unroll
    for (int k = 0; k < 16; ++k) {
        const int e   = tid + 256 * k;
        float4 wv = *(const float4*)&W[e * 4];
        const int row = e >> 5;
        const int col = (e & 31) * 4;
        ushort4 hv, lv;
        hv.x = f2bf(wv.x); lv.x = f2bf(wv.x - bf2f(hv.x));
        hv.y = f2bf(wv.y); lv.y = f2bf(wv.y - bf2f(hv.y));
        hv.z = f2bf(wv.z); lv.z = f2bf(wv.z - bf2f(hv.z));
        hv.w = f2bf(wv.w); lv.w = f2bf(wv.w - bf2f(hv.w));
        *(ushort4*)&Whs[row * 136 + col] = hv;
        *(ushort4*)&Wls[row * 136 + col] = lv;
    }
    __syncthreads();

    const int w    = tid >> 6;
    const int lane = tid & 63;
    const int fr   = lane & 15, fk = lane >> 4;
    const int n    = n0 + w * 16 + fr;

    short8 bh[4], bl[4];
    const float* xrow = &x[((size_t)(b * NN) + n) * CC];
    #pragma unroll
    for (int ks = 0; ks < 4; ++ks) {
        float xv[8];
        *(float4*)&xv[0] = *(const float4*)&xrow[(ks * 4 + fk) * 8];
        *(float4*)&xv[4] = *(const float4*)&xrow[(ks * 4 + fk) * 8 + 4];
        #pragma unroll
        for (int e = 0; e < 8; ++e) {
            unsigned short h = f2bf(xv[e]);
            bh[ks][e] = (short)h;
            bl[ks][e] = (short)f2bf(xv[e] - bf2f(h));
        }
    }

    f32x4 acc[8];
    #pragma unroll
    for (int dt = 0; dt < 8; ++dt) acc[dt] = (f32x4){0.f, 0.f, 0.f, 0.f};

    #pragma unroll
    for (int dt = 0; dt < 8; ++dt) {
        #pragma unroll
        for (int ks = 0; ks < 4; ++ks) {
            const int off = (dt * 16 + fr) * 136 + (ks * 4 + fk) * 8;
            short8 aH = *(const short8*)&Whs[off];
            short8 aL = *(const short8*)&Wls[off];
            acc[dt] = __builtin_amdgcn_mfma_f32_16x16x32_bf16(aH, bh[ks], acc[dt], 0, 0, 0);
            acc[dt] = __builtin_amdgcn_mfma_f32_16x16x32_bf16(aH, bl[ks], acc[dt], 0, 0, 0);
            acc[dt] = __builtin_amdgcn_mfma_f32_16x16x32_bf16(aL, bh[ks], acc[dt], 0, 0, 0);
        }
    }

    float p1 = 0.f, p2 = 0.f;
    #pragma unroll
    for (int dt = 0; dt < 8; ++dt) {
        #pragma unroll
        for (int r = 0; r < 4; ++r) {
            const int d = dt * 16 + fk * 4 + r;
            p1 += acc[dt][r] * a[d];
            p2 += acc[dt][r] * a[DD + d];
        }
    }
    p1 += __shfl_xor(p1, 16); p1 += __shfl_xor(p1, 32);
    p2 += __shfl_xor(p2, 16); p2 += __shfl_xor(p2, 32);
    if (fk == 0) {
        f1[b * NN + n]  = p1;
        E2g[b * NN + n] = __expf(p2);
        G2g[b * NN + n] = __expf(0.2f * p2);
    }

    #pragma unroll
    for (int dt = 0; dt < 8; ++dt) {
        #pragma unroll
        for (int r = 0; r < 4; ++r) {
            const int d = dt * 16 + fk * 4 + r;
            WhbT[((size_t)(b * 128 + d)) * NN + n] = f2bf(acc[dt][r]);
        }
    }
}

// ---------------- Kernel C: single-pass MFMA attention. Block = 64 i x 128 d x ALL j.
// 8 waves (2x4), double-buffered Bs/Ps (1 barrier/chunk), XCD-swizzled b = blk&7,
// DIRECT out via LDS transpose. No reduce kernel, no partials.
__global__ __launch_bounds__(512) void gat_kernel(
    const unsigned short* __restrict__ WhbT,   // [b][128 d][2048 n] bf16
    const unsigned int* __restrict__ padj,     // [2048][64] bitmask
    const float* __restrict__ f1,
    const float* __restrict__ E2g, const float* __restrict__ G2g,
    float* __restrict__ out)
{
    constexpr int NC = NN / 64;                 // 32 chunks
    // layout: [Bs0 16K][Bs1 16K][Ps0 8K][Ps1 8K][E2s 8K][G2s 8K][Srow/Sred]
    __shared__ __align__(16) unsigned char smem[66048];
    unsigned short* Bs0 = (unsigned short*)smem;
    unsigned short* Bs1 = (unsigned short*)(smem + 16384);
    unsigned short* Ps0 = (unsigned short*)(smem + 32768);
    unsigned short* Ps1 = (unsigned short*)(smem + 40960);
    float* E2s  = (float*)(smem + 49152);
    float* G2s  = (float*)(smem + 57344);
    float* Srow = (float*)(smem + 65536);
    float* Sred = (float*)(smem + 65792);
    float* T    = (float*)smem;                 // aliases tiles after final barrier

    const int tid  = threadIdx.x;
    const int gblk = blockIdx.x;
    const int b    = gblk & 7;                  // XCD-locality
    const int i0   = (gblk >> 3) * 64;

    #pragma unroll
    for (int k = 0; k < NN / 512; ++k) {
        E2s[tid + 512 * k] = E2g[b * NN + tid + 512 * k];
        G2s[tid + 512 * k] = G2g[b * NN + tid + 512 * k];
    }

    // P role
    const int prow = tid >> 3;
    const int pjb  = tid & 7;
    const float f1r = f1[b * NN + i0 + prow];
    const float E1r = __expf(f1r);
    const float G1r = __expf(0.2f * f1r);
    const int psw = ((pjb ^ (prow & 7)) << 3);
    const unsigned int* padjRow = padj + (size_t)(i0 + prow) * 64;

    // MFMA role
    const int w    = tid >> 6;
    const int wr   = w >> 2, wc = w & 3;
    const int lane = tid & 63;
    const int fr   = lane & 15;
    const int fk   = lane >> 4;
    f32x4 acc00 = {0.f,0.f,0.f,0.f}, acc01 = {0.f,0.f,0.f,0.f};
    f32x4 acc10 = {0.f,0.f,0.f,0.f}, acc11 = {0.f,0.f,0.f,0.f};
    float s_part = 0.f;

    // B staging maps (proven swizzle)
    const size_t wbase = (size_t)b * 128 * NN;
    const int g0 = tid,       gd0 = g0 >> 3, gj0 = (g0 & 7) * 8;
    const int g1 = tid + 512, gd1 = g1 >> 3, gj1 = (g1 & 7) * 8;
    const int sw0 = gd0 * 64 + ((((g0) & 7) ^ (gd0 & 7)) << 3);
    const int sw1 = gd1 * 64 + ((((g1) & 7) ^ (gd1 & 7)) << 3);

    uint4 brA0, brA1, brB0, brB1;
    unsigned int pwA, pwB;

#define LOADSET(s, c) do {                                                   \
        br##s##0 = *(const uint4*)&WhbT[wbase + (size_t)gd0 * NN + (c) * 64 + gj0]; \
        br##s##1 = *(const uint4*)&WhbT[wbase + (size_t)gd1 * NN + (c) * 64 + gj1]; \
        pw##s    = padjRow[(c) * 2 + (pjb >> 2)];                            \
    } while (0)

#define PSTAGE(Bsb, Psb, s, c) do {                                          \
        float4 eA = *(const float4*)&E2s[(c) * 64 + pjb * 8];                \
        float4 eB = *(const float4*)&E2s[(c) * 64 + pjb * 8 + 4];            \
        float4 gA = *(const float4*)&G2s[(c) * 64 + pjb * 8];                \
        float4 gB = *(const float4*)&G2s[(c) * 64 + pjb * 8 + 4];            \
        float ev[8], gv[8];                                                  \
        *(float4*)&ev[0] = eA; *(float4*)&ev[4] = eB;                        \
        *(float4*)&gv[0] = gA; *(float4*)&gv[4] = gB;                        \
        unsigned int pbits = (pw##s >> ((pjb & 3) << 3)) & 0xffu;            \
        unsigned short pks[8];                                               \
        float ssum = 0.f;                                                    \
        _Pragma("unroll")                                                    \
        for (int e = 0; e < 8; ++e) {                                        \
            float mv = E1r * ev[e];                                          \
            float gg = G1r * gv[e];                                          \
            float wv = fmaxf(mv, gg);                                        \
            wv = ((pbits >> e) & 1u) ? wv : 0.f;                             \
            unsigned short bw = f2bf(wv);                                    \
            pks[e] = bw;                                                     \
            ssum += bf2f(bw);                                                \
        }                                                                    \
        s_part += ssum;                                                      \
        *(uint4*)&Bsb[sw0] = br##s##0;                                       \
        *(uint4*)&Bsb[sw1] = br##s##1;                                       \
        uint4 pv;                                                            \
        pv.x = (unsigned int)pks[0] | ((unsigned int)pks[1] << 16);          \
        pv.y = (unsigned int)pks[2] | ((unsigned int)pks[3] << 16);          \
        pv.z = (unsigned int)pks[4] | ((unsigned int)pks[5] << 16);          \
        pv.w = (unsigned int)pks[6] | ((unsigned int)pks[7] << 16);          \
        *(uint4*)&Psb[prow * 64 + psw] = pv;                                 \
    } while (0)

#define MFMAC(Bsb, Psb) do {                                                 \
        __builtin_amdgcn_s_setprio(1);                                       \
        _Pragma("unroll")                                                    \
        for (int ks = 0; ks < 2; ++ks) {                                     \
            const int jbl = ks * 4 + fk;                                     \
            const int sb  = ((jbl ^ (fr & 7)) << 3);                         \
            short8 aF0 = *(const short8*)&Psb[(wr * 32 + fr) * 64 + sb];     \
            short8 aF1 = *(const short8*)&Psb[(wr * 32 + 16 + fr) * 64 + sb];\
            short8 bF0 = *(const short8*)&Bsb[(wc * 32 + fr) * 64 + sb];     \
            short8 bF1 = *(const short8*)&Bsb[(wc * 32 + 16 + fr) * 64 + sb];\
            acc00 = __builtin_amdgcn_mfma_f32_16x16x32_bf16(aF0, bF0, acc00, 0, 0, 0); \
            acc01 = __builtin_amdgcn_mfma_f32_16x16x32_bf16(aF0, bF1, acc01, 0, 0, 0); \
            acc10 = __builtin_amdgcn_mfma_f32_16x16x32_bf16(aF1, bF0, acc10, 0, 0, 0); \
            acc11 = __builtin_amdgcn_mfma_f32_16x16x32_bf16(aF1, bF1, acc11, 0, 0, 0); \
        }                                                                    \
        __builtin_amdgcn_s_setprio(0);                                       \
    } while (0)

    // prologue: chunk0 -> buf0; prefetch chunk1
    LOADSET(A, 0);
    __syncthreads();                 // E2s/G2s ready (PSTAGE reads them)
    PSTAGE(Bs0, Ps0, A, 0);
    LOADSET(B, 1);
    __syncthreads();                 // buf0 ready

    #pragma unroll 1
    for (int cc = 0; cc < NC; cc += 2) {
        // even: stage cc+1 -> buf1, prefetch cc+2, MFMA(cc) on buf0
        PSTAGE(Bs1, Ps1, B, cc + 1);
        if (cc + 2 < NC) LOADSET(A, cc + 2);
        MFMAC(Bs0, Ps0);
        __syncthreads();
        // odd: stage cc+2 -> buf0, prefetch cc+3, MFMA(cc+1) on buf1
        if (cc + 2 < NC) PSTAGE(Bs0, Ps0, A, cc + 2);
        if (cc + 3 < NC) LOADSET(B, cc + 3);
        MFMAC(Bs1, Ps1);
        __syncthreads();
    }

#undef LOADSET
#undef PSTAGE
#undef MFMAC

    // row-sum: 8 threads per row
    {
        float v = s_part;
        v += __shfl_xor(v, 1); v += __shfl_xor(v, 2); v += __shfl_xor(v, 4);
        if (pjb == 0) Srow[prow] = v;
    }
    __syncthreads();
    if (tid < 64) Sred[tid] = 1.0f / Srow[tid];
    __syncthreads();

    // normalize + elu into T (aliases tile buffers; all MFMA reads done)
    #pragma unroll
    for (int it = 0; it < 2; ++it) {
        #pragma unroll
        for (int dt = 0; dt < 2; ++dt) {
            f32x4 av = (it == 0) ? (dt == 0 ? acc00 : acc01)
                                 : (dt == 0 ? acc10 : acc11);
            #pragma unroll
            for (int r = 0; r < 4; ++r) {
                const int i = wr * 32 + it * 16 + fk * 4 + r;
                const int d = wc * 32 + dt * 16 + fr;
                float hv = av[r] * Sred[i];
                hv = (hv > 0.f) ? hv : expm1f(hv);
                T[i * 132 + d] = hv;
            }
        }
    }
    __syncthreads();

    #pragma unroll
    for (int k = 0; k < 4; ++k) {
        const int g   = tid + 512 * k;     // 2048 float4 = 64 x 128
        const int row = g >> 5;
        const int d4  = (g & 31) * 4;
        float4 h = *(const float4*)&T[row * 132 + d4];
        *(float4*)&out[((size_t)(b * NN) + i0 + row) * DD + d4] = h;
    }
}

extern "C" void kernel_launch(void* const* d_in, const int* in_sizes, int n_in,
                              void* d_out, int out_size, void* d_ws, size_t ws_size,
                              hipStream_t stream) {
    const float* x   = (const float*)d_in[0];
    const int*   adj = (const int*)d_in[1];
    const float* W   = (const float*)d_in[2];
    const float* a   = (const float*)d_in[3];
    float* out = (float*)d_out;

    char* p = (char*)d_ws;
    unsigned short* WhbT = (unsigned short*)p; p += (size_t)BB * NN * DD * 2;  // 4 MB
    float* f1  = (float*)p; p += (size_t)BB * NN * 4;                          // 64 KB
    float* E2g = (float*)p; p += (size_t)BB * NN * 4;                          // 64 KB
    float* G2g = (float*)p; p += (size_t)BB * NN * 4;                          // 64 KB
    unsigned int* padj = (unsigned int*)p;    p += (size_t)NN * 64 * 4;        // 512 KB

    prep_wh_kernel<<<PACKB + (NN / 64) * BB, 256, 0, stream>>>(
        adj, padj, x, W, a, WhbT, f1, E2g, G2g);
    gat_kernel<<<(NN / 64) * BB, 512, 0, stream>>>(
        WhbT, padj, f1, E2g, G2g, out);
}